// Round 2
// baseline (355.234 us; speedup 1.0000x reference)
//
#include <hip/hip_runtime.h>
#include <hip/hip_bf16.h>
#include <cmath>

typedef __attribute__((ext_vector_type(8))) short bf16x8;
typedef __attribute__((ext_vector_type(4))) float f32x4;

#define NXC 1024
#define NH 16
#define HD 64
#define BATCH 2
#define SEQ 2048
#define TOK (BATCH * SEQ)

__device__ __forceinline__ ushort f2bf(float f) {
  union { float f; unsigned u; } v; v.f = f;
  unsigned u = v.u;
  unsigned r = (u + 0x7FFFu + ((u >> 16) & 1u)) >> 16;  // RNE
  return (ushort)r;
}

__device__ __forceinline__ void gload_lds16(const void* g, void* lds) {
  __builtin_amdgcn_global_load_lds(
      (const __attribute__((address_space(1))) void*)g,
      (__attribute__((address_space(3))) void*)lds, 16, 0, 0);
}

// ---------------- fp32 -> bf16 convert (X) ----------------
__global__ __launch_bounds__(256) void k_convert(const float* __restrict__ in,
                                                 ushort* __restrict__ out) {
  int i = (blockIdx.x * 256 + threadIdx.x) * 4;
  float4 v = *(const float4*)(in + i);
  ushort4 o;
  o.x = f2bf(v.x); o.y = f2bf(v.y); o.z = f2bf(v.z); o.w = f2bf(v.w);
  *(ushort4*)(out + i) = o;
}

// ---------------- W [K][N] fp32 -> Wt [N][K] bf16 ----------------
__global__ __launch_bounds__(256) void k_transpose_w(const float* __restrict__ in,
                                                     ushort* __restrict__ out,
                                                     int Kd, int Nd) {
  __shared__ float t[32][33];
  int n0 = blockIdx.x * 32, k0 = blockIdx.y * 32;
  int tx = threadIdx.x & 31, ty = threadIdx.x >> 5;
#pragma unroll
  for (int r = 0; r < 4; ++r)
    t[tx][ty + r * 8] = in[(size_t)(k0 + ty + r * 8) * Nd + n0 + tx];
  __syncthreads();
  int nl = threadIdx.x >> 3, kq = (threadIdx.x & 7) * 4;
  ushort4 o;
  o.x = f2bf(t[nl][kq + 0]);
  o.y = f2bf(t[nl][kq + 1]);
  o.z = f2bf(t[nl][kq + 2]);
  o.w = f2bf(t[nl][kq + 3]);
  *(ushort4*)&out[(size_t)(n0 + nl) * Kd + k0 + kq] = o;
}

// ---------------- V [b][h][s][d] -> [b][h][d][s] (bf16) ----------------
__global__ __launch_bounds__(256) void k_transpose_v(const ushort* __restrict__ in,
                                                     ushort* __restrict__ out) {
  __shared__ ushort t[32][33];
  int bh = blockIdx.z;
  int s0 = blockIdx.x * 32, d0 = blockIdx.y * 32;
  const ushort* ip = in + (size_t)bh * SEQ * HD;
  ushort* op = out + (size_t)bh * HD * SEQ;
  int tx = threadIdx.x & 31, ty = threadIdx.x >> 5;
#pragma unroll
  for (int r = 0; r < 4; ++r)
    t[tx][ty + r * 8] = ip[(size_t)(s0 + ty + r * 8) * HD + d0 + tx];
  __syncthreads();
  int dl = threadIdx.x >> 3, sq = (threadIdx.x & 7) * 4;
  ushort4 o;
  o.x = t[dl][sq + 0]; o.y = t[dl][sq + 1];
  o.z = t[dl][sq + 2]; o.w = t[dl][sq + 3];
  *(ushort4*)&op[(size_t)(d0 + dl) * SEQ + s0 + sq] = o;
}

// ---------------- QKV GEMM: C = Xb * Wt^T + b, scatter to q/k/v ----------------
__global__ __launch_bounds__(256) void k_gemm_qkv(const ushort* __restrict__ A,
                                                  const ushort* __restrict__ Bt,
                                                  const float* __restrict__ bias,
                                                  ushort* __restrict__ q_ws,
                                                  ushort* __restrict__ k_ws,
                                                  ushort* __restrict__ v_tmp) {
  __shared__ ushort As[128 * 64];
  __shared__ ushort Bs[128 * 64];
  const int tid = threadIdx.x;
  const int wave = tid >> 6, lane = tid & 63;
  const int m0 = blockIdx.x * 128, n0 = blockIdx.y * 128;
  const int wr = (wave >> 1) * 64, wc = (wave & 1) * 64;
  const int l15 = lane & 15, lg = lane >> 4;
  f32x4 acc[4][4] = {};
  for (int k0 = 0; k0 < 1024; k0 += 64) {
#pragma unroll
    for (int c = 0; c < 4; ++c) {
      int offB = wave * 4096 + c * 1024 + lane * 16;
      int row = offB >> 7, colB = offB & 127;
      gload_lds16((const char*)A + (size_t)(m0 + row) * 2048 + k0 * 2 + colB,
                  (char*)As + wave * 4096 + c * 1024);
      gload_lds16((const char*)Bt + (size_t)(n0 + row) * 2048 + k0 * 2 + colB,
                  (char*)Bs + wave * 4096 + c * 1024);
    }
    __syncthreads();
#pragma unroll
    for (int kc = 0; kc < 2; ++kc) {
      bf16x8 af[4], bfr[4];
#pragma unroll
      for (int i = 0; i < 4; ++i)
        af[i] = *(const bf16x8*)&As[(wr + i * 16 + l15) * 64 + kc * 32 + lg * 8];
#pragma unroll
      for (int j = 0; j < 4; ++j)
        bfr[j] = *(const bf16x8*)&Bs[(wc + j * 16 + l15) * 64 + kc * 32 + lg * 8];
#pragma unroll
      for (int i = 0; i < 4; ++i)
#pragma unroll
        for (int j = 0; j < 4; ++j)
          acc[i][j] = __builtin_amdgcn_mfma_f32_16x16x32_bf16(af[i], bfr[j], acc[i][j], 0, 0, 0);
    }
    __syncthreads();
  }
#pragma unroll
  for (int j = 0; j < 4; ++j) {
    int col = n0 + wc + j * 16 + l15;
    float bv = bias[col];
    int sec = col >> 10;
    int within = col & 1023;
    int head = within >> 6, d = within & 63;
#pragma unroll
    for (int i = 0; i < 4; ++i) {
#pragma unroll
      for (int r = 0; r < 4; ++r) {
        int row = m0 + wr + i * 16 + lg * 4 + r;
        int b = row >> 11, s = row & 2047;
        float val = acc[i][j][r] + bv;
        size_t base = ((size_t)(b * NH + head) * SEQ + s) * HD + d;
        if (sec == 0)      q_ws[base] = f2bf(val * 0.125f);
        else if (sec == 1) k_ws[base] = f2bf(val);
        else               v_tmp[base] = f2bf(val);
      }
    }
  }
}

// ---------------- flash attention (causal), barrier-free ----------------
// K/V fragments read directly from global (L1/L2-resident); only the
// per-wave P re-layout goes through LDS (XOR-swizzled).
__global__ __launch_bounds__(256) void k_attn(const ushort* __restrict__ q_ws,
                                              const ushort* __restrict__ k_ws,
                                              const ushort* __restrict__ v_ws,
                                              ushort* __restrict__ a_ws) {
  __shared__ ushort Ps[4][16 * 64];
  const int qt = 31 - blockIdx.x;   // longest blocks dispatch first
  const int bh = blockIdx.y;
  const int tid = threadIdx.x, wave = tid >> 6, lane = tid & 63;
  const int l15 = lane & 15, lg = lane >> 4;
  const ushort* qp = q_ws + (size_t)bh * SEQ * HD;
  const ushort* kp = k_ws + (size_t)bh * SEQ * HD;
  const ushort* vp = v_ws + (size_t)bh * HD * SEQ;
  ushort* Pw = Ps[wave];
  bf16x8 qf[2];
  {
    int qrow = qt * 64 + wave * 16 + l15;
    qf[0] = *(const bf16x8*)&qp[(size_t)qrow * HD + 0 + lg * 8];
    qf[1] = *(const bf16x8*)&qp[(size_t)qrow * HD + 32 + lg * 8];
  }
  f32x4 o[4] = {};
  float m_r[4] = {-INFINITY, -INFINITY, -INFINITY, -INFINITY};
  float l_r[4] = {0.f, 0.f, 0.f, 0.f};
  for (int kt = 0; kt <= qt; ++kt) {
    const bool diag = (kt == qt);
    f32x4 sc[4] = {};
    __builtin_amdgcn_s_setprio(1);
#pragma unroll
    for (int f = 0; f < 4; ++f) {
      if (diag && f > wave) continue;  // fully-masked fragment
      const ushort* kr = kp + (size_t)(kt * 64 + f * 16 + l15) * HD;
      bf16x8 kf0 = *(const bf16x8*)(kr + lg * 8);
      bf16x8 kf1 = *(const bf16x8*)(kr + 32 + lg * 8);
      sc[f] = __builtin_amdgcn_mfma_f32_16x16x32_bf16(qf[0], kf0, sc[f], 0, 0, 0);
      sc[f] = __builtin_amdgcn_mfma_f32_16x16x32_bf16(qf[1], kf1, sc[f], 0, 0, 0);
    }
    __builtin_amdgcn_s_setprio(0);
    if (diag) {
#pragma unroll
      for (int f = 0; f < 4; ++f) {
        int key_rel = f * 16 + l15;
#pragma unroll
        for (int r = 0; r < 4; ++r) {
          int q_rel = wave * 16 + lg * 4 + r;
          if (key_rel > q_rel) sc[f][r] = -1e30f;
        }
      }
    }
    float rmax[4], rsum[4], alpha[4];
#pragma unroll
    for (int r = 0; r < 4; ++r)
      rmax[r] = fmaxf(fmaxf(sc[0][r], sc[1][r]), fmaxf(sc[2][r], sc[3][r]));
#pragma unroll
    for (int off = 1; off < 16; off <<= 1)
#pragma unroll
      for (int r = 0; r < 4; ++r)
        rmax[r] = fmaxf(rmax[r], __shfl_xor(rmax[r], off));
#pragma unroll
    for (int r = 0; r < 4; ++r) {
      float mn = fmaxf(m_r[r], rmax[r]);
      alpha[r] = __expf(m_r[r] - mn);
      m_r[r] = mn;
      rsum[r] = 0.f;
    }
#pragma unroll
    for (int f = 0; f < 4; ++f)
#pragma unroll
      for (int r = 0; r < 4; ++r) {
        float p = __expf(sc[f][r] - m_r[r]);
        sc[f][r] = p;
        rsum[r] += p;
      }
#pragma unroll
    for (int off = 1; off < 16; off <<= 1)
#pragma unroll
      for (int r = 0; r < 4; ++r)
        rsum[r] += __shfl_xor(rsum[r], off);
#pragma unroll
    for (int r = 0; r < 4; ++r)
      l_r[r] = l_r[r] * alpha[r] + rsum[r];
    // P (C-frag) -> bf16 -> per-wave swizzled LDS -> A-frag
#pragma unroll
    for (int f = 0; f < 4; ++f)
#pragma unroll
      for (int r = 0; r < 4; ++r) {
        int q = lg * 4 + r;
        Pw[q * 64 + ((f * 16 + l15) ^ ((q & 7) << 3))] = f2bf(sc[f][r]);
      }
#pragma unroll
    for (int df = 0; df < 4; ++df)
#pragma unroll
      for (int r = 0; r < 4; ++r)
        o[df][r] *= alpha[r];
    __builtin_amdgcn_s_setprio(1);
#pragma unroll
    for (int kc = 0; kc < 2; ++kc) {
      bf16x8 pf = *(const bf16x8*)&Pw[l15 * 64 + ((kc * 32 + lg * 8) ^ ((l15 & 7) << 3))];
#pragma unroll
      for (int df = 0; df < 4; ++df) {
        bf16x8 vf = *(const bf16x8*)&vp[(size_t)(df * 16 + l15) * SEQ + kt * 64 + kc * 32 + lg * 8];
        o[df] = __builtin_amdgcn_mfma_f32_16x16x32_bf16(pf, vf, o[df], 0, 0, 0);
      }
    }
    __builtin_amdgcn_s_setprio(0);
  }
  int b = bh >> 4, head = bh & 15;
#pragma unroll
  for (int r = 0; r < 4; ++r) {
    float inv = 1.0f / l_r[r];
    int s = qt * 64 + wave * 16 + lg * 4 + r;
#pragma unroll
    for (int df = 0; df < 4; ++df) {
      int col = head * 64 + df * 16 + l15;
      a_ws[((size_t)(b * SEQ + s)) * NXC + col] = f2bf(o[df][r] * inv);
    }
  }
}

// ---------------- out-proj GEMM: out = A * Wt^T + b (fp32 out) ----------------
__global__ __launch_bounds__(256) void k_gemm_proj(const ushort* __restrict__ A,
                                                   const ushort* __restrict__ Bt,
                                                   const float* __restrict__ bias,
                                                   float* __restrict__ out) {
  __shared__ ushort As[128 * 64];
  __shared__ ushort Bs[128 * 64];
  const int tid = threadIdx.x;
  const int wave = tid >> 6, lane = tid & 63;
  const int m0 = blockIdx.x * 128, n0 = blockIdx.y * 128;
  const int wr = (wave >> 1) * 64, wc = (wave & 1) * 64;
  const int l15 = lane & 15, lg = lane >> 4;
  f32x4 acc[4][4] = {};
  for (int k0 = 0; k0 < 1024; k0 += 64) {
#pragma unroll
    for (int c = 0; c < 4; ++c) {
      int offB = wave * 4096 + c * 1024 + lane * 16;
      int row = offB >> 7, colB = offB & 127;
      gload_lds16((const char*)A + (size_t)(m0 + row) * 2048 + k0 * 2 + colB,
                  (char*)As + wave * 4096 + c * 1024);
      gload_lds16((const char*)Bt + (size_t)(n0 + row) * 2048 + k0 * 2 + colB,
                  (char*)Bs + wave * 4096 + c * 1024);
    }
    __syncthreads();
#pragma unroll
    for (int kc = 0; kc < 2; ++kc) {
      bf16x8 af[4], bfr[4];
#pragma unroll
      for (int i = 0; i < 4; ++i)
        af[i] = *(const bf16x8*)&As[(wr + i * 16 + l15) * 64 + kc * 32 + lg * 8];
#pragma unroll
      for (int j = 0; j < 4; ++j)
        bfr[j] = *(const bf16x8*)&Bs[(wc + j * 16 + l15) * 64 + kc * 32 + lg * 8];
#pragma unroll
      for (int i = 0; i < 4; ++i)
#pragma unroll
        for (int j = 0; j < 4; ++j)
          acc[i][j] = __builtin_amdgcn_mfma_f32_16x16x32_bf16(af[i], bfr[j], acc[i][j], 0, 0, 0);
    }
    __syncthreads();
  }
#pragma unroll
  for (int j = 0; j < 4; ++j) {
    int col = n0 + wc + j * 16 + l15;
    float bv = bias[col];
#pragma unroll
    for (int i = 0; i < 4; ++i) {
#pragma unroll
      for (int r = 0; r < 4; ++r) {
        int row = m0 + wr + i * 16 + lg * 4 + r;
        out[(size_t)row * NXC + col] = acc[i][j][r] + bv;
      }
    }
  }
}

extern "C" void kernel_launch(void* const* d_in, const int* in_sizes, int n_in,
                              void* d_out, int out_size, void* d_ws, size_t ws_size,
                              hipStream_t stream) {
  const float* hs       = (const float*)d_in[0];
  const float* c_attn_w = (const float*)d_in[1];
  const float* c_attn_b = (const float*)d_in[2];
  const float* c_proj_w = (const float*)d_in[3];
  const float* c_proj_b = (const float*)d_in[4];
  char* ws = (char*)d_ws;
  const size_t MB = 1 << 20;
  ushort* Xb      = (ushort*)(ws + 0 * MB);   // [4096][1024]
  ushort* Wt_attn = (ushort*)(ws + 8 * MB);   // [3072][1024]
  ushort* Wt_proj = (ushort*)(ws + 14 * MB);  // [1024][1024]
  ushort* q_ws    = (ushort*)(ws + 16 * MB);  // [b][h][s][d]
  ushort* k_ws    = (ushort*)(ws + 24 * MB);  // [b][h][s][d]
  ushort* v_ws    = (ushort*)(ws + 32 * MB);  // [b][h][d][s]
  ushort* a_ws    = (ushort*)(ws + 40 * MB);  // [4096][1024]; also v_tmp before attn
  ushort* v_tmp   = a_ws;

  k_convert<<<4096, 256, 0, stream>>>(hs, Xb);
  k_transpose_w<<<dim3(96, 32), 256, 0, stream>>>(c_attn_w, Wt_attn, 1024, 3072);
  k_transpose_w<<<dim3(32, 32), 256, 0, stream>>>(c_proj_w, Wt_proj, 1024, 1024);
  k_gemm_qkv<<<dim3(32, 24), 256, 0, stream>>>(Xb, Wt_attn, c_attn_b, q_ws, k_ws, v_tmp);
  k_transpose_v<<<dim3(64, 2, 32), 256, 0, stream>>>(v_tmp, v_ws);
  k_attn<<<dim3(32, 32), 256, 0, stream>>>(q_ws, k_ws, v_ws, a_ws);
  k_gemm_proj<<<dim3(32, 8), 256, 0, stream>>>(a_ws, Wt_proj, c_proj_b, (float*)d_out);
}

// Round 3
// 216.263 us; speedup vs baseline: 1.6426x; 1.6426x over previous
//
#include <hip/hip_runtime.h>
#include <hip/hip_bf16.h>
#include <cmath>

typedef __attribute__((ext_vector_type(8))) short bf16x8;
typedef __attribute__((ext_vector_type(4))) float f32x4;

#define NXC 1024
#define NH 16
#define HD 64
#define BATCH 2
#define SEQ 2048
#define TOK (BATCH * SEQ)

__device__ __forceinline__ ushort f2bf(float f) {
  union { float f; unsigned u; } v; v.f = f;
  unsigned u = v.u;
  unsigned r = (u + 0x7FFFu + ((u >> 16) & 1u)) >> 16;  // RNE
  return (ushort)r;
}

__device__ __forceinline__ void gload_lds16(const void* g, void* lds) {
  __builtin_amdgcn_global_load_lds(
      (const __attribute__((address_space(1))) void*)g,
      (__attribute__((address_space(3))) void*)lds, 16, 0, 0);
}

// ---------------- fp32 -> bf16 convert (X) ----------------
__global__ __launch_bounds__(256) void k_convert(const float* __restrict__ in,
                                                 ushort* __restrict__ out) {
  int i = (blockIdx.x * 256 + threadIdx.x) * 4;
  float4 v = *(const float4*)(in + i);
  ushort4 o;
  o.x = f2bf(v.x); o.y = f2bf(v.y); o.z = f2bf(v.z); o.w = f2bf(v.w);
  *(ushort4*)(out + i) = o;
}

// ---------------- W [K][N] fp32 -> Wt [N][K] bf16 ----------------
__global__ __launch_bounds__(256) void k_transpose_w(const float* __restrict__ in,
                                                     ushort* __restrict__ out,
                                                     int Kd, int Nd) {
  __shared__ float t[32][33];
  int n0 = blockIdx.x * 32, k0 = blockIdx.y * 32;
  int tx = threadIdx.x & 31, ty = threadIdx.x >> 5;
#pragma unroll
  for (int r = 0; r < 4; ++r)
    t[tx][ty + r * 8] = in[(size_t)(k0 + ty + r * 8) * Nd + n0 + tx];
  __syncthreads();
  int nl = threadIdx.x >> 3, kq = (threadIdx.x & 7) * 4;
  ushort4 o;
  o.x = f2bf(t[nl][kq + 0]);
  o.y = f2bf(t[nl][kq + 1]);
  o.z = f2bf(t[nl][kq + 2]);
  o.w = f2bf(t[nl][kq + 3]);
  *(ushort4*)&out[(size_t)(n0 + nl) * Kd + k0 + kq] = o;
}

// ---------------- V [b][h][s][d] -> [b][h][d][s] (bf16), swizzled ----------------
// output element (d, key) stored at key ^ ((d&7)<<3)  (within each 64-key tile)
__global__ __launch_bounds__(256) void k_transpose_v(const ushort* __restrict__ in,
                                                     ushort* __restrict__ out) {
  __shared__ ushort t[32][33];
  int bh = blockIdx.z;
  int s0 = blockIdx.x * 32, d0 = blockIdx.y * 32;
  const ushort* ip = in + (size_t)bh * SEQ * HD;
  ushort* op = out + (size_t)bh * HD * SEQ;
  int tx = threadIdx.x & 31, ty = threadIdx.x >> 5;
#pragma unroll
  for (int r = 0; r < 4; ++r)
    t[tx][ty + r * 8] = ip[(size_t)(s0 + ty + r * 8) * HD + d0 + tx];
  __syncthreads();
  int dl = threadIdx.x >> 3, sq = (threadIdx.x & 7) * 4;
  ushort4 o;
  o.x = t[dl][sq + 0]; o.y = t[dl][sq + 1];
  o.z = t[dl][sq + 2]; o.w = t[dl][sq + 3];
  int key = (s0 + sq) ^ ((dl & 7) << 3);   // XOR hits bits 3-5 only; 4-elem run intact
  *(ushort4*)&op[(size_t)(d0 + dl) * SEQ + key] = o;
}

// ---------------- QKV GEMM: C = Xb * Wt^T + b, scatter to q/k/v ----------------
// K is stored PRE-SWIZZLED: element (s,d) at d ^ ((s&7)<<3)
__global__ __launch_bounds__(256) void k_gemm_qkv(const ushort* __restrict__ A,
                                                  const ushort* __restrict__ Bt,
                                                  const float* __restrict__ bias,
                                                  ushort* __restrict__ q_ws,
                                                  ushort* __restrict__ k_ws,
                                                  ushort* __restrict__ v_tmp) {
  __shared__ ushort As[128 * 64];
  __shared__ ushort Bs[128 * 64];
  const int tid = threadIdx.x;
  const int wave = tid >> 6, lane = tid & 63;
  const int m0 = blockIdx.x * 128, n0 = blockIdx.y * 128;
  const int wr = (wave >> 1) * 64, wc = (wave & 1) * 64;
  const int l15 = lane & 15, lg = lane >> 4;
  f32x4 acc[4][4] = {};
  for (int k0 = 0; k0 < 1024; k0 += 64) {
#pragma unroll
    for (int c = 0; c < 4; ++c) {
      int offB = wave * 4096 + c * 1024 + lane * 16;
      int row = offB >> 7, colB = offB & 127;
      gload_lds16((const char*)A + (size_t)(m0 + row) * 2048 + k0 * 2 + colB,
                  (char*)As + wave * 4096 + c * 1024);
      gload_lds16((const char*)Bt + (size_t)(n0 + row) * 2048 + k0 * 2 + colB,
                  (char*)Bs + wave * 4096 + c * 1024);
    }
    __syncthreads();
#pragma unroll
    for (int kc = 0; kc < 2; ++kc) {
      bf16x8 af[4], bfr[4];
#pragma unroll
      for (int i = 0; i < 4; ++i)
        af[i] = *(const bf16x8*)&As[(wr + i * 16 + l15) * 64 + kc * 32 + lg * 8];
#pragma unroll
      for (int j = 0; j < 4; ++j)
        bfr[j] = *(const bf16x8*)&Bs[(wc + j * 16 + l15) * 64 + kc * 32 + lg * 8];
#pragma unroll
      for (int i = 0; i < 4; ++i)
#pragma unroll
        for (int j = 0; j < 4; ++j)
          acc[i][j] = __builtin_amdgcn_mfma_f32_16x16x32_bf16(af[i], bfr[j], acc[i][j], 0, 0, 0);
    }
    __syncthreads();
  }
#pragma unroll
  for (int j = 0; j < 4; ++j) {
    int col = n0 + wc + j * 16 + l15;
    float bv = bias[col];
    int sec = col >> 10;
    int within = col & 1023;
    int head = within >> 6, d = within & 63;
#pragma unroll
    for (int i = 0; i < 4; ++i) {
#pragma unroll
      for (int r = 0; r < 4; ++r) {
        int row = m0 + wr + i * 16 + lg * 4 + r;
        int b = row >> 11, s = row & 2047;
        float val = acc[i][j][r] + bv;
        size_t hb = ((size_t)(b * NH + head) * SEQ + s) * HD;
        if (sec == 0)      q_ws[hb + d] = f2bf(val * 0.125f);
        else if (sec == 1) k_ws[hb + (d ^ ((s & 7) << 3))] = f2bf(val);
        else               v_tmp[hb + d] = f2bf(val);
      }
    }
  }
}

// ---------------- flash attention (causal), dbuf staging + swizzled LDS ----------------
__global__ __launch_bounds__(256) void k_attn(const ushort* __restrict__ q_ws,
                                              const ushort* __restrict__ k_ws,
                                              const ushort* __restrict__ v_ws,
                                              ushort* __restrict__ a_ws) {
  __shared__ ushort Ks[2][64 * 64];
  __shared__ ushort Vs[2][64 * 64];   // [d][key], key pre-swizzled
  __shared__ ushort Ps[4][16 * 64];   // per-wave P tile, swizzled
  const int qt = 31 - blockIdx.x;     // longest blocks dispatch first
  const int bh = blockIdx.y;
  const int tid = threadIdx.x, wave = tid >> 6, lane = tid & 63;
  const int l15 = lane & 15, lg = lane >> 4;
  const int swz = (l15 & 7) << 3;     // element-index XOR for row=l15 reads
  const ushort* qp = q_ws + (size_t)bh * SEQ * HD;
  const ushort* kp = k_ws + (size_t)bh * SEQ * HD;
  const ushort* vp = v_ws + (size_t)bh * HD * SEQ;
  ushort* Pw = Ps[wave];
  bf16x8 qf[2];
  {
    int qrow = qt * 64 + wave * 16 + l15;
    qf[0] = *(const bf16x8*)&qp[(size_t)qrow * HD + lg * 8];
    qf[1] = *(const bf16x8*)&qp[(size_t)qrow * HD + 32 + lg * 8];
  }
  f32x4 o[4] = {};
  float m_r[4] = {-INFINITY, -INFINITY, -INFINITY, -INFINITY};
  float l_r[4] = {0.f, 0.f, 0.f, 0.f};

  auto stage = [&](int kt, int buf) {
#pragma unroll
    for (int c = 0; c < 2; ++c) {
      int offB = wave * 2048 + c * 1024 + lane * 16;
      gload_lds16((const char*)kp + (size_t)kt * 8192 + offB,
                  (char*)Ks[buf] + offB);
      int d = offB >> 7, keyB = offB & 127;
      gload_lds16((const char*)vp + (size_t)d * (SEQ * 2) + (size_t)kt * 128 + keyB,
                  (char*)Vs[buf] + offB);
    }
  };

  stage(0, 0);
  asm volatile("s_waitcnt vmcnt(0)" ::: "memory");
  __syncthreads();

  for (int kt = 0; kt <= qt; ++kt) {
    const int cur = kt & 1;
    const bool diag = (kt == qt);
    if (kt < qt) stage(kt + 1, cur ^ 1);   // prefetch next tile (other buffer)
    const ushort* Kc = Ks[cur];
    const ushort* Vc = Vs[cur];
    f32x4 sc[4] = {};
#pragma unroll
    for (int kc = 0; kc < 2; ++kc)
#pragma unroll
      for (int f = 0; f < 4; ++f) {
        if (diag && f > wave) continue;  // fully-masked fragment
        bf16x8 kf = *(const bf16x8*)&Kc[(f * 16 + l15) * 64 + ((kc * 32 + lg * 8) ^ swz)];
        sc[f] = __builtin_amdgcn_mfma_f32_16x16x32_bf16(qf[kc], kf, sc[f], 0, 0, 0);
      }
    if (diag) {
#pragma unroll
      for (int f = 0; f < 4; ++f) {
        int key_rel = f * 16 + l15;
#pragma unroll
        for (int r = 0; r < 4; ++r) {
          int q_rel = wave * 16 + lg * 4 + r;
          if (key_rel > q_rel) sc[f][r] = -1e30f;
        }
      }
    }
    float rmax[4], rsum[4], alpha[4];
#pragma unroll
    for (int r = 0; r < 4; ++r)
      rmax[r] = fmaxf(fmaxf(sc[0][r], sc[1][r]), fmaxf(sc[2][r], sc[3][r]));
#pragma unroll
    for (int off = 1; off < 16; off <<= 1)
#pragma unroll
      for (int r = 0; r < 4; ++r)
        rmax[r] = fmaxf(rmax[r], __shfl_xor(rmax[r], off));
#pragma unroll
    for (int r = 0; r < 4; ++r) {
      float mn = fmaxf(m_r[r], rmax[r]);
      alpha[r] = __expf(m_r[r] - mn);
      m_r[r] = mn;
      rsum[r] = 0.f;
    }
#pragma unroll
    for (int f = 0; f < 4; ++f)
#pragma unroll
      for (int r = 0; r < 4; ++r) {
        float p = __expf(sc[f][r] - m_r[r]);
        sc[f][r] = p;
        rsum[r] += p;
      }
#pragma unroll
    for (int off = 1; off < 16; off <<= 1)
#pragma unroll
      for (int r = 0; r < 4; ++r)
        rsum[r] += __shfl_xor(rsum[r], off);
#pragma unroll
    for (int r = 0; r < 4; ++r)
      l_r[r] = l_r[r] * alpha[r] + rsum[r];
    // P (C-frag) -> bf16 -> per-wave swizzled LDS -> A-frag
#pragma unroll
    for (int f = 0; f < 4; ++f)
#pragma unroll
      for (int r = 0; r < 4; ++r) {
        int q = lg * 4 + r;
        Pw[q * 64 + ((f * 16 + l15) ^ ((q & 7) << 3))] = f2bf(sc[f][r]);
      }
#pragma unroll
    for (int df = 0; df < 4; ++df)
#pragma unroll
      for (int r = 0; r < 4; ++r)
        o[df][r] *= alpha[r];
#pragma unroll
    for (int kc = 0; kc < 2; ++kc) {
      bf16x8 pf = *(const bf16x8*)&Pw[l15 * 64 + ((kc * 32 + lg * 8) ^ swz)];
#pragma unroll
      for (int df = 0; df < 4; ++df) {
        bf16x8 vf = *(const bf16x8*)&Vc[(df * 16 + l15) * 64 + ((kc * 32 + lg * 8) ^ swz)];
        o[df] = __builtin_amdgcn_mfma_f32_16x16x32_bf16(pf, vf, o[df], 0, 0, 0);
      }
    }
    asm volatile("s_waitcnt vmcnt(0)" ::: "memory");
    __syncthreads();
  }
  int b = bh >> 4, head = bh & 15;
#pragma unroll
  for (int r = 0; r < 4; ++r) {
    float inv = 1.0f / l_r[r];
    int s = qt * 64 + wave * 16 + lg * 4 + r;
#pragma unroll
    for (int df = 0; df < 4; ++df) {
      int col = head * 64 + df * 16 + l15;
      a_ws[((size_t)(b * SEQ + s)) * NXC + col] = f2bf(o[df][r] * inv);
    }
  }
}

// ---------------- out-proj GEMM: out = A * Wt^T + b (fp32 out) ----------------
__global__ __launch_bounds__(256) void k_gemm_proj(const ushort* __restrict__ A,
                                                   const ushort* __restrict__ Bt,
                                                   const float* __restrict__ bias,
                                                   float* __restrict__ out) {
  __shared__ ushort As[128 * 64];
  __shared__ ushort Bs[128 * 64];
  const int tid = threadIdx.x;
  const int wave = tid >> 6, lane = tid & 63;
  const int m0 = blockIdx.x * 128, n0 = blockIdx.y * 128;
  const int wr = (wave >> 1) * 64, wc = (wave & 1) * 64;
  const int l15 = lane & 15, lg = lane >> 4;
  f32x4 acc[4][4] = {};
  for (int k0 = 0; k0 < 1024; k0 += 64) {
#pragma unroll
    for (int c = 0; c < 4; ++c) {
      int offB = wave * 4096 + c * 1024 + lane * 16;
      int row = offB >> 7, colB = offB & 127;
      gload_lds16((const char*)A + (size_t)(m0 + row) * 2048 + k0 * 2 + colB,
                  (char*)As + wave * 4096 + c * 1024);
      gload_lds16((const char*)Bt + (size_t)(n0 + row) * 2048 + k0 * 2 + colB,
                  (char*)Bs + wave * 4096 + c * 1024);
    }
    __syncthreads();
#pragma unroll
    for (int kc = 0; kc < 2; ++kc) {
      bf16x8 af[4], bfr[4];
#pragma unroll
      for (int i = 0; i < 4; ++i)
        af[i] = *(const bf16x8*)&As[(wr + i * 16 + l15) * 64 + kc * 32 + lg * 8];
#pragma unroll
      for (int j = 0; j < 4; ++j)
        bfr[j] = *(const bf16x8*)&Bs[(wc + j * 16 + l15) * 64 + kc * 32 + lg * 8];
#pragma unroll
      for (int i = 0; i < 4; ++i)
#pragma unroll
        for (int j = 0; j < 4; ++j)
          acc[i][j] = __builtin_amdgcn_mfma_f32_16x16x32_bf16(af[i], bfr[j], acc[i][j], 0, 0, 0);
    }
    __syncthreads();
  }
#pragma unroll
  for (int j = 0; j < 4; ++j) {
    int col = n0 + wc + j * 16 + l15;
    float bv = bias[col];
#pragma unroll
    for (int i = 0; i < 4; ++i) {
#pragma unroll
      for (int r = 0; r < 4; ++r) {
        int row = m0 + wr + i * 16 + lg * 4 + r;
        out[(size_t)row * NXC + col] = acc[i][j][r] + bv;
      }
    }
  }
}

extern "C" void kernel_launch(void* const* d_in, const int* in_sizes, int n_in,
                              void* d_out, int out_size, void* d_ws, size_t ws_size,
                              hipStream_t stream) {
  const float* hs       = (const float*)d_in[0];
  const float* c_attn_w = (const float*)d_in[1];
  const float* c_attn_b = (const float*)d_in[2];
  const float* c_proj_w = (const float*)d_in[3];
  const float* c_proj_b = (const float*)d_in[4];
  char* ws = (char*)d_ws;
  const size_t MB = 1 << 20;
  ushort* Xb      = (ushort*)(ws + 0 * MB);   // [4096][1024]
  ushort* Wt_attn = (ushort*)(ws + 8 * MB);   // [3072][1024]
  ushort* Wt_proj = (ushort*)(ws + 14 * MB);  // [1024][1024]
  ushort* q_ws    = (ushort*)(ws + 16 * MB);  // [b][h][s][d]
  ushort* k_ws    = (ushort*)(ws + 24 * MB);  // [b][h][s][d], d pre-swizzled
  ushort* v_ws    = (ushort*)(ws + 32 * MB);  // [b][h][d][s], key pre-swizzled
  ushort* a_ws    = (ushort*)(ws + 40 * MB);  // [4096][1024]; also v_tmp before attn
  ushort* v_tmp   = a_ws;

  k_convert<<<4096, 256, 0, stream>>>(hs, Xb);
  k_transpose_w<<<dim3(96, 32), 256, 0, stream>>>(c_attn_w, Wt_attn, 1024, 3072);
  k_transpose_w<<<dim3(32, 32), 256, 0, stream>>>(c_proj_w, Wt_proj, 1024, 1024);
  k_gemm_qkv<<<dim3(32, 24), 256, 0, stream>>>(Xb, Wt_attn, c_attn_b, q_ws, k_ws, v_tmp);
  k_transpose_v<<<dim3(64, 2, 32), 256, 0, stream>>>(v_tmp, v_ws);
  k_attn<<<dim3(32, 32), 256, 0, stream>>>(q_ws, k_ws, v_ws, a_ws);
  k_gemm_proj<<<dim3(32, 8), 256, 0, stream>>>(a_ws, Wt_proj, c_proj_b, (float*)d_out);
}

// Round 4
// 179.173 us; speedup vs baseline: 1.9826x; 1.2070x over previous
//
#include <hip/hip_runtime.h>
#include <hip/hip_bf16.h>
#include <cmath>

typedef __attribute__((ext_vector_type(8))) short bf16x8;
typedef __attribute__((ext_vector_type(4))) float f32x4;

#define NXC 1024
#define NH 16
#define HD 64
#define BATCH 2
#define SEQ 2048
#define TOK (BATCH * SEQ)

__device__ __forceinline__ ushort f2bf(float f) {
  union { float f; unsigned u; } v; v.f = f;
  unsigned u = v.u;
  unsigned r = (u + 0x7FFFu + ((u >> 16) & 1u)) >> 16;  // RNE
  return (ushort)r;
}

__device__ __forceinline__ void gload_lds16(const void* g, void* lds) {
  __builtin_amdgcn_global_load_lds(
      (const __attribute__((address_space(1))) void*)g,
      (__attribute__((address_space(3))) void*)lds, 16, 0, 0);
}

__device__ __forceinline__ float fast_exp2(float x) {
  float r;
  asm("v_exp_f32 %0, %1" : "=v"(r) : "v"(x));
  return r;
}

template <int CTRL>
__device__ __forceinline__ float dpp_mov(float x) {
  return __builtin_bit_cast(
      float, __builtin_amdgcn_mov_dpp(__builtin_bit_cast(int, x), CTRL, 0xF, 0xF, true));
}
// reduce across the 16 contiguous lanes of a DPP row (row_ror 1,2,4,8)
__device__ __forceinline__ float red16_max(float x) {
  x = fmaxf(x, dpp_mov<0x121>(x));
  x = fmaxf(x, dpp_mov<0x122>(x));
  x = fmaxf(x, dpp_mov<0x124>(x));
  x = fmaxf(x, dpp_mov<0x128>(x));
  return x;
}
__device__ __forceinline__ float red16_sum(float x) {
  x += dpp_mov<0x121>(x);
  x += dpp_mov<0x122>(x);
  x += dpp_mov<0x124>(x);
  x += dpp_mov<0x128>(x);
  return x;
}

// ---------------- fp32 -> bf16 convert (X) ----------------
__global__ __launch_bounds__(256) void k_convert(const float* __restrict__ in,
                                                 ushort* __restrict__ out) {
  int i = (blockIdx.x * 256 + threadIdx.x) * 4;
  float4 v = *(const float4*)(in + i);
  ushort4 o;
  o.x = f2bf(v.x); o.y = f2bf(v.y); o.z = f2bf(v.z); o.w = f2bf(v.w);
  *(ushort4*)(out + i) = o;
}

// ---------------- W [K][N] fp32 -> Wt [N][K] bf16 ----------------
__global__ __launch_bounds__(256) void k_transpose_w(const float* __restrict__ in,
                                                     ushort* __restrict__ out,
                                                     int Kd, int Nd) {
  __shared__ float t[32][33];
  int n0 = blockIdx.x * 32, k0 = blockIdx.y * 32;
  int tx = threadIdx.x & 31, ty = threadIdx.x >> 5;
#pragma unroll
  for (int r = 0; r < 4; ++r)
    t[tx][ty + r * 8] = in[(size_t)(k0 + ty + r * 8) * Nd + n0 + tx];
  __syncthreads();
  int nl = threadIdx.x >> 3, kq = (threadIdx.x & 7) * 4;
  ushort4 o;
  o.x = f2bf(t[nl][kq + 0]);
  o.y = f2bf(t[nl][kq + 1]);
  o.z = f2bf(t[nl][kq + 2]);
  o.w = f2bf(t[nl][kq + 3]);
  *(ushort4*)&out[(size_t)(n0 + nl) * Kd + k0 + kq] = o;
}

// ---------------- V [b][h][s][d] -> [b][h][d][s] (bf16), swizzled ----------------
__global__ __launch_bounds__(256) void k_transpose_v(const ushort* __restrict__ in,
                                                     ushort* __restrict__ out) {
  __shared__ ushort t[32][33];
  int bh = blockIdx.z;
  int s0 = blockIdx.x * 32, d0 = blockIdx.y * 32;
  const ushort* ip = in + (size_t)bh * SEQ * HD;
  ushort* op = out + (size_t)bh * HD * SEQ;
  int tx = threadIdx.x & 31, ty = threadIdx.x >> 5;
#pragma unroll
  for (int r = 0; r < 4; ++r)
    t[tx][ty + r * 8] = ip[(size_t)(s0 + ty + r * 8) * HD + d0 + tx];
  __syncthreads();
  int dl = threadIdx.x >> 3, sq = (threadIdx.x & 7) * 4;
  ushort4 o;
  o.x = t[dl][sq + 0]; o.y = t[dl][sq + 1];
  o.z = t[dl][sq + 2]; o.w = t[dl][sq + 3];
  int key = (s0 + sq) ^ ((dl & 7) << 3);   // XOR hits bits 3-5 only; 4-elem run intact
  *(ushort4*)&op[(size_t)(d0 + dl) * SEQ + key] = o;
}

// ---------------- QKV GEMM: C = Xb * Wt^T + b, scatter to q/k/v ----------------
// Q pre-scaled by log2(e)/8 (attention runs in exp2 domain);
// K stored PRE-SWIZZLED: element (s,d) at d ^ ((s&7)<<3)
__global__ __launch_bounds__(256) void k_gemm_qkv(const ushort* __restrict__ A,
                                                  const ushort* __restrict__ Bt,
                                                  const float* __restrict__ bias,
                                                  ushort* __restrict__ q_ws,
                                                  ushort* __restrict__ k_ws,
                                                  ushort* __restrict__ v_tmp) {
  __shared__ ushort As[128 * 64];
  __shared__ ushort Bs[128 * 64];
  const int tid = threadIdx.x;
  const int wave = tid >> 6, lane = tid & 63;
  const int m0 = blockIdx.x * 128, n0 = blockIdx.y * 128;
  const int wr = (wave >> 1) * 64, wc = (wave & 1) * 64;
  const int l15 = lane & 15, lg = lane >> 4;
  f32x4 acc[4][4] = {};
  for (int k0 = 0; k0 < 1024; k0 += 64) {
#pragma unroll
    for (int c = 0; c < 4; ++c) {
      int offB = wave * 4096 + c * 1024 + lane * 16;
      int row = offB >> 7, colB = offB & 127;
      gload_lds16((const char*)A + (size_t)(m0 + row) * 2048 + k0 * 2 + colB,
                  (char*)As + wave * 4096 + c * 1024);
      gload_lds16((const char*)Bt + (size_t)(n0 + row) * 2048 + k0 * 2 + colB,
                  (char*)Bs + wave * 4096 + c * 1024);
    }
    __syncthreads();
#pragma unroll
    for (int kc = 0; kc < 2; ++kc) {
      bf16x8 af[4], bfr[4];
#pragma unroll
      for (int i = 0; i < 4; ++i)
        af[i] = *(const bf16x8*)&As[(wr + i * 16 + l15) * 64 + kc * 32 + lg * 8];
#pragma unroll
      for (int j = 0; j < 4; ++j)
        bfr[j] = *(const bf16x8*)&Bs[(wc + j * 16 + l15) * 64 + kc * 32 + lg * 8];
#pragma unroll
      for (int i = 0; i < 4; ++i)
#pragma unroll
        for (int j = 0; j < 4; ++j)
          acc[i][j] = __builtin_amdgcn_mfma_f32_16x16x32_bf16(af[i], bfr[j], acc[i][j], 0, 0, 0);
    }
    __syncthreads();
  }
#pragma unroll
  for (int j = 0; j < 4; ++j) {
    int col = n0 + wc + j * 16 + l15;
    float bv = bias[col];
    int sec = col >> 10;
    int within = col & 1023;
    int head = within >> 6, d = within & 63;
#pragma unroll
    for (int i = 0; i < 4; ++i) {
#pragma unroll
      for (int r = 0; r < 4; ++r) {
        int row = m0 + wr + i * 16 + lg * 4 + r;
        int b = row >> 11, s = row & 2047;
        float val = acc[i][j][r] + bv;
        size_t hb = ((size_t)(b * NH + head) * SEQ + s) * HD;
        if (sec == 0)      q_ws[hb + d] = f2bf(val * 0.1803368801f);  // log2(e)/8
        else if (sec == 1) k_ws[hb + (d ^ ((s & 7) << 3))] = f2bf(val);
        else               v_tmp[hb + d] = f2bf(val);
      }
    }
  }
}

// ---------------- flash attention (causal), exp2-domain, DPP softmax ----------------
__global__ __launch_bounds__(256) void k_attn(const ushort* __restrict__ q_ws,
                                              const ushort* __restrict__ k_ws,
                                              const ushort* __restrict__ v_ws,
                                              ushort* __restrict__ a_ws) {
  __shared__ ushort Ks[2][64 * 64];
  __shared__ ushort Vs[2][64 * 64];   // [d][key], key pre-swizzled
  __shared__ ushort Ps[4][16 * 64];   // per-wave P tile, swizzled
  const int qt = 31 - blockIdx.x;     // longest blocks dispatch first
  const int bh = blockIdx.y;
  const int tid = threadIdx.x, wave = tid >> 6, lane = tid & 63;
  const int l15 = lane & 15, lg = lane >> 4;
  const int swz = (l15 & 7) << 3;     // element-index XOR for row=l15 reads
  const ushort* qp = q_ws + (size_t)bh * SEQ * HD;
  const ushort* kp = k_ws + (size_t)bh * SEQ * HD;
  const ushort* vp = v_ws + (size_t)bh * HD * SEQ;
  ushort* Pw = Ps[wave];
  bf16x8 qf[2];
  {
    int qrow = qt * 64 + wave * 16 + l15;
    qf[0] = *(const bf16x8*)&qp[(size_t)qrow * HD + lg * 8];
    qf[1] = *(const bf16x8*)&qp[(size_t)qrow * HD + 32 + lg * 8];
  }
  f32x4 o[4] = {};
  float m_r[4] = {-INFINITY, -INFINITY, -INFINITY, -INFINITY};
  float l_r[4] = {0.f, 0.f, 0.f, 0.f};

  auto stage = [&](int kt, int buf) {
#pragma unroll
    for (int c = 0; c < 2; ++c) {
      int offB = wave * 2048 + c * 1024 + lane * 16;
      gload_lds16((const char*)kp + (size_t)kt * 8192 + offB,
                  (char*)Ks[buf] + offB);
      int d = offB >> 7, keyB = offB & 127;
      gload_lds16((const char*)vp + (size_t)d * (SEQ * 2) + (size_t)kt * 128 + keyB,
                  (char*)Vs[buf] + offB);
    }
  };

  stage(0, 0);
  asm volatile("s_waitcnt vmcnt(0)" ::: "memory");
  __syncthreads();

  for (int kt = 0; kt <= qt; ++kt) {
    const int cur = kt & 1;
    const bool diag = (kt == qt);
    if (kt < qt) stage(kt + 1, cur ^ 1);   // prefetch next tile (other buffer)
    const ushort* Kc = Ks[cur];
    const ushort* Vc = Vs[cur];
    f32x4 sc[4] = {};
#pragma unroll
    for (int kc = 0; kc < 2; ++kc)
#pragma unroll
      for (int f = 0; f < 4; ++f) {
        if (diag && f > wave) continue;  // fully-masked fragment
        bf16x8 kf = *(const bf16x8*)&Kc[(f * 16 + l15) * 64 + ((kc * 32 + lg * 8) ^ swz)];
        sc[f] = __builtin_amdgcn_mfma_f32_16x16x32_bf16(qf[kc], kf, sc[f], 0, 0, 0);
      }
    if (diag) {
#pragma unroll
      for (int f = 0; f < 4; ++f) {
        int key_rel = f * 16 + l15;
#pragma unroll
        for (int r = 0; r < 4; ++r) {
          int q_rel = wave * 16 + lg * 4 + r;
          if (key_rel > q_rel) sc[f][r] = -1e30f;
        }
      }
    }
    // tile row-max (in-reg over f, then DPP across the 16-lane row group)
    float pmax[4];
#pragma unroll
    for (int r = 0; r < 4; ++r)
      pmax[r] = red16_max(fmaxf(fmaxf(sc[0][r], sc[1][r]), fmaxf(sc[2][r], sc[3][r])));
    // defer-max (T13): rescale only when the running max grew by > 8 (exp2 domain)
    bool resc = false;
#pragma unroll
    for (int r = 0; r < 4; ++r) resc |= (pmax[r] > m_r[r] + 8.f);
    if (__any(resc)) {
#pragma unroll
      for (int r = 0; r < 4; ++r) {
        float mn = fmaxf(m_r[r], pmax[r]);
        float al = fast_exp2(m_r[r] - mn);
        m_r[r] = mn;
        l_r[r] *= al;
#pragma unroll
        for (int df = 0; df < 4; ++df) o[df][r] *= al;
      }
    }
    // P = exp2(sc - m), row-sum
    float rsum[4] = {0.f, 0.f, 0.f, 0.f};
#pragma unroll
    for (int f = 0; f < 4; ++f)
#pragma unroll
      for (int r = 0; r < 4; ++r) {
        float p = fast_exp2(sc[f][r] - m_r[r]);
        sc[f][r] = p;
        rsum[r] += p;
      }
    // P (C-frag) -> bf16 -> per-wave swizzled LDS -> A-frag
#pragma unroll
    for (int f = 0; f < 4; ++f)
#pragma unroll
      for (int r = 0; r < 4; ++r) {
        int q = lg * 4 + r;
        Pw[q * 64 + ((f * 16 + l15) ^ ((q & 7) << 3))] = f2bf(sc[f][r]);
      }
#pragma unroll
    for (int r = 0; r < 4; ++r)
      l_r[r] += red16_sum(rsum[r]);
#pragma unroll
    for (int kc = 0; kc < 2; ++kc) {
      bf16x8 pf = *(const bf16x8*)&Pw[l15 * 64 + ((kc * 32 + lg * 8) ^ swz)];
#pragma unroll
      for (int df = 0; df < 4; ++df) {
        bf16x8 vf = *(const bf16x8*)&Vc[(df * 16 + l15) * 64 + ((kc * 32 + lg * 8) ^ swz)];
        o[df] = __builtin_amdgcn_mfma_f32_16x16x32_bf16(pf, vf, o[df], 0, 0, 0);
      }
    }
    asm volatile("s_waitcnt vmcnt(0)" ::: "memory");
    __syncthreads();
  }
  int b = bh >> 4, head = bh & 15;
#pragma unroll
  for (int r = 0; r < 4; ++r) {
    float inv = 1.0f / l_r[r];
    int s = qt * 64 + wave * 16 + lg * 4 + r;
#pragma unroll
    for (int df = 0; df < 4; ++df) {
      int col = head * 64 + df * 16 + l15;
      a_ws[((size_t)(b * SEQ + s)) * NXC + col] = f2bf(o[df][r] * inv);
    }
  }
}

// ---------------- out-proj GEMM: out = A * Wt^T + b (fp32 out) ----------------
__global__ __launch_bounds__(256) void k_gemm_proj(const ushort* __restrict__ A,
                                                   const ushort* __restrict__ Bt,
                                                   const float* __restrict__ bias,
                                                   float* __restrict__ out) {
  __shared__ ushort As[128 * 64];
  __shared__ ushort Bs[128 * 64];
  const int tid = threadIdx.x;
  const int wave = tid >> 6, lane = tid & 63;
  const int m0 = blockIdx.x * 128, n0 = blockIdx.y * 128;
  const int wr = (wave >> 1) * 64, wc = (wave & 1) * 64;
  const int l15 = lane & 15, lg = lane >> 4;
  f32x4 acc[4][4] = {};
  for (int k0 = 0; k0 < 1024; k0 += 64) {
#pragma unroll
    for (int c = 0; c < 4; ++c) {
      int offB = wave * 4096 + c * 1024 + lane * 16;
      int row = offB >> 7, colB = offB & 127;
      gload_lds16((const char*)A + (size_t)(m0 + row) * 2048 + k0 * 2 + colB,
                  (char*)As + wave * 4096 + c * 1024);
      gload_lds16((const char*)Bt + (size_t)(n0 + row) * 2048 + k0 * 2 + colB,
                  (char*)Bs + wave * 4096 + c * 1024);
    }
    __syncthreads();
#pragma unroll
    for (int kc = 0; kc < 2; ++kc) {
      bf16x8 af[4], bfr[4];
#pragma unroll
      for (int i = 0; i < 4; ++i)
        af[i] = *(const bf16x8*)&As[(wr + i * 16 + l15) * 64 + kc * 32 + lg * 8];
#pragma unroll
      for (int j = 0; j < 4; ++j)
        bfr[j] = *(const bf16x8*)&Bs[(wc + j * 16 + l15) * 64 + kc * 32 + lg * 8];
#pragma unroll
      for (int i = 0; i < 4; ++i)
#pragma unroll
        for (int j = 0; j < 4; ++j)
          acc[i][j] = __builtin_amdgcn_mfma_f32_16x16x32_bf16(af[i], bfr[j], acc[i][j], 0, 0, 0);
    }
    __syncthreads();
  }
#pragma unroll
  for (int j = 0; j < 4; ++j) {
    int col = n0 + wc + j * 16 + l15;
    float bv = bias[col];
#pragma unroll
    for (int i = 0; i < 4; ++i) {
#pragma unroll
      for (int r = 0; r < 4; ++r) {
        int row = m0 + wr + i * 16 + lg * 4 + r;
        out[(size_t)row * NXC + col] = acc[i][j][r] + bv;
      }
    }
  }
}

extern "C" void kernel_launch(void* const* d_in, const int* in_sizes, int n_in,
                              void* d_out, int out_size, void* d_ws, size_t ws_size,
                              hipStream_t stream) {
  const float* hs       = (const float*)d_in[0];
  const float* c_attn_w = (const float*)d_in[1];
  const float* c_attn_b = (const float*)d_in[2];
  const float* c_proj_w = (const float*)d_in[3];
  const float* c_proj_b = (const float*)d_in[4];
  char* ws = (char*)d_ws;
  const size_t MB = 1 << 20;
  ushort* Xb      = (ushort*)(ws + 0 * MB);   // [4096][1024]
  ushort* Wt_attn = (ushort*)(ws + 8 * MB);   // [3072][1024]
  ushort* Wt_proj = (ushort*)(ws + 14 * MB);  // [1024][1024]
  ushort* q_ws    = (ushort*)(ws + 16 * MB);  // [b][h][s][d], exp2-scaled
  ushort* k_ws    = (ushort*)(ws + 24 * MB);  // [b][h][s][d], d pre-swizzled
  ushort* v_ws    = (ushort*)(ws + 32 * MB);  // [b][h][d][s], key pre-swizzled
  ushort* a_ws    = (ushort*)(ws + 40 * MB);  // [4096][1024]; also v_tmp before attn
  ushort* v_tmp   = a_ws;

  k_convert<<<4096, 256, 0, stream>>>(hs, Xb);
  k_transpose_w<<<dim3(96, 32), 256, 0, stream>>>(c_attn_w, Wt_attn, 1024, 3072);
  k_transpose_w<<<dim3(32, 32), 256, 0, stream>>>(c_proj_w, Wt_proj, 1024, 1024);
  k_gemm_qkv<<<dim3(32, 24), 256, 0, stream>>>(Xb, Wt_attn, c_attn_b, q_ws, k_ws, v_tmp);
  k_transpose_v<<<dim3(64, 2, 32), 256, 0, stream>>>(v_tmp, v_ws);
  k_attn<<<dim3(32, 32), 256, 0, stream>>>(q_ws, k_ws, v_ws, a_ws);
  k_gemm_proj<<<dim3(32, 8), 256, 0, stream>>>(a_ws, Wt_proj, c_proj_b, (float*)d_out);
}

// Round 5
// 155.431 us; speedup vs baseline: 2.2855x; 1.1527x over previous
//
#include <hip/hip_runtime.h>
#include <hip/hip_bf16.h>
#include <cmath>

typedef __attribute__((ext_vector_type(8))) short bf16x8;
typedef __attribute__((ext_vector_type(4))) float f32x4;

#define NXC 1024
#define NH 16
#define HD 64
#define BATCH 2
#define SEQ 2048
#define TOK (BATCH * SEQ)

__device__ __forceinline__ ushort f2bf(float f) {
  union { float f; unsigned u; } v; v.f = f;
  unsigned u = v.u;
  unsigned r = (u + 0x7FFFu + ((u >> 16) & 1u)) >> 16;  // RNE
  return (ushort)r;
}

__device__ __forceinline__ void gload_lds16(const void* g, void* lds) {
  __builtin_amdgcn_global_load_lds(
      (const __attribute__((address_space(1))) void*)g,
      (__attribute__((address_space(3))) void*)lds, 16, 0, 0);
}

__device__ __forceinline__ float fast_exp2(float x) {
  float r;
  asm("v_exp_f32 %0, %1" : "=v"(r) : "v"(x));
  return r;
}

template <int CTRL>
__device__ __forceinline__ float dpp_mov(float x) {
  return __builtin_bit_cast(
      float, __builtin_amdgcn_mov_dpp(__builtin_bit_cast(int, x), CTRL, 0xF, 0xF, true));
}
// reduce across the 16 contiguous lanes of a DPP row (row_ror 1,2,4,8)
__device__ __forceinline__ float red16_max(float x) {
  x = fmaxf(x, dpp_mov<0x121>(x));
  x = fmaxf(x, dpp_mov<0x122>(x));
  x = fmaxf(x, dpp_mov<0x124>(x));
  x = fmaxf(x, dpp_mov<0x128>(x));
  return x;
}
__device__ __forceinline__ float red16_sum(float x) {
  x += dpp_mov<0x121>(x);
  x += dpp_mov<0x122>(x);
  x += dpp_mov<0x124>(x);
  x += dpp_mov<0x128>(x);
  return x;
}

// ---------------- fp32 -> bf16 convert (X) ----------------
__global__ __launch_bounds__(256) void k_convert(const float* __restrict__ in,
                                                 ushort* __restrict__ out) {
  int i = (blockIdx.x * 256 + threadIdx.x) * 4;
  float4 v = *(const float4*)(in + i);
  ushort4 o;
  o.x = f2bf(v.x); o.y = f2bf(v.y); o.z = f2bf(v.z); o.w = f2bf(v.w);
  *(ushort4*)(out + i) = o;
}

// ---------------- W [K][N] fp32 -> Wt [N][K] bf16 ----------------
__global__ __launch_bounds__(256) void k_transpose_w(const float* __restrict__ in,
                                                     ushort* __restrict__ out,
                                                     int Kd, int Nd) {
  __shared__ float t[32][33];
  int n0 = blockIdx.x * 32, k0 = blockIdx.y * 32;
  int tx = threadIdx.x & 31, ty = threadIdx.x >> 5;
#pragma unroll
  for (int r = 0; r < 4; ++r)
    t[tx][ty + r * 8] = in[(size_t)(k0 + ty + r * 8) * Nd + n0 + tx];
  __syncthreads();
  int nl = threadIdx.x >> 3, kq = (threadIdx.x & 7) * 4;
  ushort4 o;
  o.x = f2bf(t[nl][kq + 0]);
  o.y = f2bf(t[nl][kq + 1]);
  o.z = f2bf(t[nl][kq + 2]);
  o.w = f2bf(t[nl][kq + 3]);
  *(ushort4*)&out[(size_t)(n0 + nl) * Kd + k0 + kq] = o;
}

// ---------------- V [b][h][s][d] -> [b][h][d][s] (bf16), swizzled ----------------
__global__ __launch_bounds__(256) void k_transpose_v(const ushort* __restrict__ in,
                                                     ushort* __restrict__ out) {
  __shared__ ushort t[32][33];
  int bh = blockIdx.z;
  int s0 = blockIdx.x * 32, d0 = blockIdx.y * 32;
  const ushort* ip = in + (size_t)bh * SEQ * HD;
  ushort* op = out + (size_t)bh * HD * SEQ;
  int tx = threadIdx.x & 31, ty = threadIdx.x >> 5;
#pragma unroll
  for (int r = 0; r < 4; ++r)
    t[tx][ty + r * 8] = ip[(size_t)(s0 + ty + r * 8) * HD + d0 + tx];
  __syncthreads();
  int dl = threadIdx.x >> 3, sq = (threadIdx.x & 7) * 4;
  ushort4 o;
  o.x = t[dl][sq + 0]; o.y = t[dl][sq + 1];
  o.z = t[dl][sq + 2]; o.w = t[dl][sq + 3];
  int key = (s0 + sq) ^ ((dl & 7) << 3);   // XOR hits bits 3-5 only; 4-elem run intact
  *(ushort4*)&op[(size_t)(d0 + dl) * SEQ + key] = o;
}

// ---------------- QKV GEMM: C = Xb * Wt^T + b, scatter to q/k/v ----------------
// Q pre-scaled by log2(e)/8 (attention runs in exp2 domain);
// K stored PRE-SWIZZLED: element (s,d) at d ^ ((s&7)<<3)
__global__ __launch_bounds__(256) void k_gemm_qkv(const ushort* __restrict__ A,
                                                  const ushort* __restrict__ Bt,
                                                  const float* __restrict__ bias,
                                                  ushort* __restrict__ q_ws,
                                                  ushort* __restrict__ k_ws,
                                                  ushort* __restrict__ v_tmp) {
  __shared__ ushort As[128 * 64];
  __shared__ ushort Bs[128 * 64];
  const int tid = threadIdx.x;
  const int wave = tid >> 6, lane = tid & 63;
  const int m0 = blockIdx.x * 128, n0 = blockIdx.y * 128;
  const int wr = (wave >> 1) * 64, wc = (wave & 1) * 64;
  const int l15 = lane & 15, lg = lane >> 4;
  f32x4 acc[4][4] = {};
  for (int k0 = 0; k0 < 1024; k0 += 64) {
#pragma unroll
    for (int c = 0; c < 4; ++c) {
      int offB = wave * 4096 + c * 1024 + lane * 16;
      int row = offB >> 7, colB = offB & 127;
      gload_lds16((const char*)A + (size_t)(m0 + row) * 2048 + k0 * 2 + colB,
                  (char*)As + wave * 4096 + c * 1024);
      gload_lds16((const char*)Bt + (size_t)(n0 + row) * 2048 + k0 * 2 + colB,
                  (char*)Bs + wave * 4096 + c * 1024);
    }
    __syncthreads();
#pragma unroll
    for (int kc = 0; kc < 2; ++kc) {
      bf16x8 af[4], bfr[4];
#pragma unroll
      for (int i = 0; i < 4; ++i)
        af[i] = *(const bf16x8*)&As[(wr + i * 16 + l15) * 64 + kc * 32 + lg * 8];
#pragma unroll
      for (int j = 0; j < 4; ++j)
        bfr[j] = *(const bf16x8*)&Bs[(wc + j * 16 + l15) * 64 + kc * 32 + lg * 8];
#pragma unroll
      for (int i = 0; i < 4; ++i)
#pragma unroll
        for (int j = 0; j < 4; ++j)
          acc[i][j] = __builtin_amdgcn_mfma_f32_16x16x32_bf16(af[i], bfr[j], acc[i][j], 0, 0, 0);
    }
    __syncthreads();
  }
#pragma unroll
  for (int j = 0; j < 4; ++j) {
    int col = n0 + wc + j * 16 + l15;
    float bv = bias[col];
    int sec = col >> 10;
    int within = col & 1023;
    int head = within >> 6, d = within & 63;
#pragma unroll
    for (int i = 0; i < 4; ++i) {
#pragma unroll
      for (int r = 0; r < 4; ++r) {
        int row = m0 + wr + i * 16 + lg * 4 + r;
        int b = row >> 11, s = row & 2047;
        float val = acc[i][j][r] + bv;
        size_t hb = ((size_t)(b * NH + head) * SEQ + s) * HD;
        if (sec == 0)      q_ws[hb + d] = f2bf(val * 0.1803368801f);  // log2(e)/8
        else if (sec == 1) k_ws[hb + (d ^ ((s & 7) << 3))] = f2bf(val);
        else               v_tmp[hb + d] = f2bf(val);
      }
    }
  }
}

// ---------------- flash attention (causal), paired mirrored Q-tiles ----------------
// Block p handles q-tiles qtA=31-p and qtB=p: every block does exactly 33
// compute-tile units (balanced grid), and both tiles share the K/V staging.
__global__ __launch_bounds__(256) void k_attn(const ushort* __restrict__ q_ws,
                                              const ushort* __restrict__ k_ws,
                                              const ushort* __restrict__ v_ws,
                                              ushort* __restrict__ a_ws) {
  __shared__ ushort Ks[2][64 * 64];
  __shared__ ushort Vs[2][64 * 64];     // [d][key], key pre-swizzled
  __shared__ ushort Ps[4][2][16 * 64];  // per-wave, per-tile P buffer (swizzled)
  const int p = blockIdx.x, bh = blockIdx.y;
  const int qtA = 31 - p, qtB = p;      // qtB < qtA always (p in [0,16))
  const int tid = threadIdx.x, wave = tid >> 6, lane = tid & 63;
  const int l15 = lane & 15, lg = lane >> 4;
  const int swz = (l15 & 7) << 3;       // element-index XOR for row=l15 reads
  const ushort* qp = q_ws + (size_t)bh * SEQ * HD;
  const ushort* kp = k_ws + (size_t)bh * SEQ * HD;
  const ushort* vp = v_ws + (size_t)bh * HD * SEQ;

  bf16x8 qfA[2], qfB[2];
  {
    int qrA = qtA * 64 + wave * 16 + l15;
    int qrB = qtB * 64 + wave * 16 + l15;
    qfA[0] = *(const bf16x8*)&qp[(size_t)qrA * HD + lg * 8];
    qfA[1] = *(const bf16x8*)&qp[(size_t)qrA * HD + 32 + lg * 8];
    qfB[0] = *(const bf16x8*)&qp[(size_t)qrB * HD + lg * 8];
    qfB[1] = *(const bf16x8*)&qp[(size_t)qrB * HD + 32 + lg * 8];
  }
  f32x4 oA[4] = {}, oB[4] = {};
  float mA[4] = {-INFINITY, -INFINITY, -INFINITY, -INFINITY};
  float mB[4] = {-INFINITY, -INFINITY, -INFINITY, -INFINITY};
  float lA[4] = {0.f, 0.f, 0.f, 0.f}, lB[4] = {0.f, 0.f, 0.f, 0.f};

  auto stage = [&](int kt, int buf) {
#pragma unroll
    for (int c = 0; c < 2; ++c) {
      int offB = wave * 2048 + c * 1024 + lane * 16;
      gload_lds16((const char*)kp + (size_t)kt * 8192 + offB,
                  (char*)Ks[buf] + offB);
      int d = offB >> 7, keyB = offB & 127;
      gload_lds16((const char*)vp + (size_t)d * (SEQ * 2) + (size_t)kt * 128 + keyB,
                  (char*)Vs[buf] + offB);
    }
  };

  auto tile_step = [&](const bf16x8* qf, f32x4* o, float* m_r, float* l_r,
                       ushort* Pw, const ushort* Kc, const ushort* Vc, bool diag) {
    f32x4 sc[4] = {};
#pragma unroll
    for (int kc = 0; kc < 2; ++kc)
#pragma unroll
      for (int f = 0; f < 4; ++f) {
        if (diag && f > wave) continue;  // fully-masked fragment
        bf16x8 kf = *(const bf16x8*)&Kc[(f * 16 + l15) * 64 + ((kc * 32 + lg * 8) ^ swz)];
        sc[f] = __builtin_amdgcn_mfma_f32_16x16x32_bf16(qf[kc], kf, sc[f], 0, 0, 0);
      }
    if (diag) {
#pragma unroll
      for (int f = 0; f < 4; ++f) {
        int key_rel = f * 16 + l15;
#pragma unroll
        for (int r = 0; r < 4; ++r) {
          int q_rel = wave * 16 + lg * 4 + r;
          if (key_rel > q_rel) sc[f][r] = -1e30f;
        }
      }
    }
    float pmax[4];
#pragma unroll
    for (int r = 0; r < 4; ++r)
      pmax[r] = red16_max(fmaxf(fmaxf(sc[0][r], sc[1][r]), fmaxf(sc[2][r], sc[3][r])));
    bool resc = false;
#pragma unroll
    for (int r = 0; r < 4; ++r) resc |= (pmax[r] > m_r[r] + 8.f);
    if (__any(resc)) {
#pragma unroll
      for (int r = 0; r < 4; ++r) {
        float mn = fmaxf(m_r[r], pmax[r]);
        float al = fast_exp2(m_r[r] - mn);
        m_r[r] = mn;
        l_r[r] *= al;
#pragma unroll
        for (int df = 0; df < 4; ++df) o[df][r] *= al;
      }
    }
    float rsum[4] = {0.f, 0.f, 0.f, 0.f};
#pragma unroll
    for (int f = 0; f < 4; ++f)
#pragma unroll
      for (int r = 0; r < 4; ++r) {
        float pv = fast_exp2(sc[f][r] - m_r[r]);
        sc[f][r] = pv;
        rsum[r] += pv;
      }
#pragma unroll
    for (int f = 0; f < 4; ++f)
#pragma unroll
      for (int r = 0; r < 4; ++r) {
        int q = lg * 4 + r;
        Pw[q * 64 + ((f * 16 + l15) ^ ((q & 7) << 3))] = f2bf(sc[f][r]);
      }
#pragma unroll
    for (int r = 0; r < 4; ++r)
      l_r[r] += red16_sum(rsum[r]);
#pragma unroll
    for (int kc = 0; kc < 2; ++kc) {
      bf16x8 pf = *(const bf16x8*)&Pw[l15 * 64 + ((kc * 32 + lg * 8) ^ swz)];
#pragma unroll
      for (int df = 0; df < 4; ++df) {
        bf16x8 vf = *(const bf16x8*)&Vc[(df * 16 + l15) * 64 + ((kc * 32 + lg * 8) ^ swz)];
        o[df] = __builtin_amdgcn_mfma_f32_16x16x32_bf16(pf, vf, o[df], 0, 0, 0);
      }
    }
  };

  stage(0, 0);
  asm volatile("s_waitcnt vmcnt(0)" ::: "memory");
  __syncthreads();

  for (int kt = 0; kt <= qtA; ++kt) {
    const int cur = kt & 1;
    if (kt < qtA) stage(kt + 1, cur ^ 1);   // prefetch next tile (other buffer)
    tile_step(qfA, oA, mA, lA, Ps[wave][0], Ks[cur], Vs[cur], kt == qtA);
    if (kt <= qtB)
      tile_step(qfB, oB, mB, lB, Ps[wave][1], Ks[cur], Vs[cur], kt == qtB);
    asm volatile("s_waitcnt vmcnt(0)" ::: "memory");
    __syncthreads();
  }

  int b = bh >> 4, head = bh & 15;
  auto epilogue = [&](f32x4* o, float* l_r, int qt) {
#pragma unroll
    for (int r = 0; r < 4; ++r) {
      float inv = 1.0f / l_r[r];
      int s = qt * 64 + wave * 16 + lg * 4 + r;
#pragma unroll
      for (int df = 0; df < 4; ++df) {
        int col = head * 64 + df * 16 + l15;
        a_ws[((size_t)(b * SEQ + s)) * NXC + col] = f2bf(o[df][r] * inv);
      }
    }
  };
  epilogue(oA, lA, qtA);
  epilogue(oB, lB, qtB);
}

// ---------------- out-proj GEMM: out = A * Wt^T + b (fp32 out) ----------------
__global__ __launch_bounds__(256) void k_gemm_proj(const ushort* __restrict__ A,
                                                   const ushort* __restrict__ Bt,
                                                   const float* __restrict__ bias,
                                                   float* __restrict__ out) {
  __shared__ ushort As[128 * 64];
  __shared__ ushort Bs[128 * 64];
  const int tid = threadIdx.x;
  const int wave = tid >> 6, lane = tid & 63;
  const int m0 = blockIdx.x * 128, n0 = blockIdx.y * 128;
  const int wr = (wave >> 1) * 64, wc = (wave & 1) * 64;
  const int l15 = lane & 15, lg = lane >> 4;
  f32x4 acc[4][4] = {};
  for (int k0 = 0; k0 < 1024; k0 += 64) {
#pragma unroll
    for (int c = 0; c < 4; ++c) {
      int offB = wave * 4096 + c * 1024 + lane * 16;
      int row = offB >> 7, colB = offB & 127;
      gload_lds16((const char*)A + (size_t)(m0 + row) * 2048 + k0 * 2 + colB,
                  (char*)As + wave * 4096 + c * 1024);
      gload_lds16((const char*)Bt + (size_t)(n0 + row) * 2048 + k0 * 2 + colB,
                  (char*)Bs + wave * 4096 + c * 1024);
    }
    __syncthreads();
#pragma unroll
    for (int kc = 0; kc < 2; ++kc) {
      bf16x8 af[4], bfr[4];
#pragma unroll
      for (int i = 0; i < 4; ++i)
        af[i] = *(const bf16x8*)&As[(wr + i * 16 + l15) * 64 + kc * 32 + lg * 8];
#pragma unroll
      for (int j = 0; j < 4; ++j)
        bfr[j] = *(const bf16x8*)&Bs[(wc + j * 16 + l15) * 64 + kc * 32 + lg * 8];
#pragma unroll
      for (int i = 0; i < 4; ++i)
#pragma unroll
        for (int j = 0; j < 4; ++j)
          acc[i][j] = __builtin_amdgcn_mfma_f32_16x16x32_bf16(af[i], bfr[j], acc[i][j], 0, 0, 0);
    }
    __syncthreads();
  }
#pragma unroll
  for (int j = 0; j < 4; ++j) {
    int col = n0 + wc + j * 16 + l15;
    float bv = bias[col];
#pragma unroll
    for (int i = 0; i < 4; ++i) {
#pragma unroll
      for (int r = 0; r < 4; ++r) {
        int row = m0 + wr + i * 16 + lg * 4 + r;
        out[(size_t)row * NXC + col] = acc[i][j][r] + bv;
      }
    }
  }
}

extern "C" void kernel_launch(void* const* d_in, const int* in_sizes, int n_in,
                              void* d_out, int out_size, void* d_ws, size_t ws_size,
                              hipStream_t stream) {
  const float* hs       = (const float*)d_in[0];
  const float* c_attn_w = (const float*)d_in[1];
  const float* c_attn_b = (const float*)d_in[2];
  const float* c_proj_w = (const float*)d_in[3];
  const float* c_proj_b = (const float*)d_in[4];
  char* ws = (char*)d_ws;
  const size_t MB = 1 << 20;
  ushort* Xb      = (ushort*)(ws + 0 * MB);   // [4096][1024]
  ushort* Wt_attn = (ushort*)(ws + 8 * MB);   // [3072][1024]
  ushort* Wt_proj = (ushort*)(ws + 14 * MB);  // [1024][1024]
  ushort* q_ws    = (ushort*)(ws + 16 * MB);  // [b][h][s][d], exp2-scaled
  ushort* k_ws    = (ushort*)(ws + 24 * MB);  // [b][h][s][d], d pre-swizzled
  ushort* v_ws    = (ushort*)(ws + 32 * MB);  // [b][h][d][s], key pre-swizzled
  ushort* a_ws    = (ushort*)(ws + 40 * MB);  // [4096][1024]; also v_tmp before attn
  ushort* v_tmp   = a_ws;

  k_convert<<<4096, 256, 0, stream>>>(hs, Xb);
  k_transpose_w<<<dim3(96, 32), 256, 0, stream>>>(c_attn_w, Wt_attn, 1024, 3072);
  k_transpose_w<<<dim3(32, 32), 256, 0, stream>>>(c_proj_w, Wt_proj, 1024, 1024);
  k_gemm_qkv<<<dim3(32, 24), 256, 0, stream>>>(Xb, Wt_attn, c_attn_b, q_ws, k_ws, v_tmp);
  k_transpose_v<<<dim3(64, 2, 32), 256, 0, stream>>>(v_tmp, v_ws);
  k_attn<<<dim3(16, 32), 256, 0, stream>>>(q_ws, k_ws, v_ws, a_ws);
  k_gemm_proj<<<dim3(32, 8), 256, 0, stream>>>(a_ws, Wt_proj, c_proj_b, (float*)d_out);
}